// Round 2
// baseline (68.351 us; speedup 1.0000x reference)
//
#include <hip/hip_runtime.h>
#include <hip/hip_bf16.h>

typedef __attribute__((ext_vector_type(8))) short bf16x8;
typedef __attribute__((ext_vector_type(4))) float f32x4;

#define NB   4
#define NN   2048
#define FIN  256
#define FOUT 128
#define SPLIT 4
#define JCH  (NN / SPLIT)      // 512 j per block
#define NSTEP (JCH / 64)       // 8 steps

__device__ __forceinline__ unsigned short f2bf(float f) {
    unsigned int u = __builtin_bit_cast(unsigned int, f);
    u += 0x7fffu + ((u >> 16) & 1u);
    return (unsigned short)(u >> 16);
}

// ---------------- Kernel 0: WT[o][k] bf16 from W[k][o] f32 ----------------
__global__ __launch_bounds__(256) void k_wt(const float* __restrict__ W,
                                            unsigned short* __restrict__ WT) {
    int idx = blockIdx.x * 256 + threadIdx.x;      // 32768 = 128*256
    int k = idx & 255, o = idx >> 8;
    WT[idx] = f2bf(W[k * FOUT + o]);
}

// ---------------- Kernel 1: Wh = h@W (MFMA), writes WhT bf16 + s1,s2 ------
// 512 blocks x 16 rows; 4 waves each own a 32-wide o-quadrant.
__global__ __launch_bounds__(256) void k_wh(const float* __restrict__ h,
                                            const float* __restrict__ a,
                                            const unsigned short* __restrict__ WT,
                                            unsigned short* __restrict__ WhT,
                                            float* __restrict__ s1,
                                            float* __restrict__ s2) {
    __shared__ unsigned short hs[16][264];         // 16 rows x 256 bf16, pad 8
    __shared__ float s1w[4][16], s2w[4][16];
    int t = threadIdx.x, blk = blockIdx.x;
    int nglob0 = blk * 16;                         // block's 16-row base
    int b = nglob0 >> 11;

    // stage 16 rows of h as bf16 into LDS (1024 float4, 4 per thread)
    const float4* h4 = (const float4*)h + (size_t)blk * 1024;
    #pragma unroll
    for (int i = 0; i < 4; ++i) {
        int idx = i * 256 + t;
        float4 v = h4[idx];
        int row = idx >> 6, c4 = (idx & 63) * 4;
        unsigned int lo = (unsigned int)f2bf(v.x) | ((unsigned int)f2bf(v.y) << 16);
        unsigned int hi = (unsigned int)f2bf(v.z) | ((unsigned int)f2bf(v.w) << 16);
        *(uint2*)&hs[row][c4] = make_uint2(lo, hi);
    }
    __syncthreads();

    int w = t >> 6, l = t & 63, lr = l & 15, lk = l >> 4;
    float a1v[2], a2v[2];
    #pragma unroll
    for (int j = 0; j < 2; ++j) {
        a1v[j] = a[(w * 2 + j) * 16 + lr];
        a2v[j] = a[FOUT + (w * 2 + j) * 16 + lr];
    }
    f32x4 acc[2] = {{0.f,0.f,0.f,0.f},{0.f,0.f,0.f,0.f}};

    #pragma unroll
    for (int kk = 0; kk < 8; ++kk) {
        int k0 = kk * 32;
        bf16x8 af = *(const bf16x8*)&hs[lr][k0 + lk * 8];
        #pragma unroll
        for (int j = 0; j < 2; ++j) {
            bf16x8 bf = *(const bf16x8*)(WT + ((w * 2 + j) * 16 + lr) * 256 + k0 + lk * 8);
            acc[j] = __builtin_amdgcn_mfma_f32_16x16x32_bf16(af, bf, acc[j], 0, 0, 0);
        }
    }

    // epilogue: write WhT bf16 (transposed) and per-wave s1/s2 partials
    int nn0 = (nglob0 & 2047) + lk * 4;
    float v1[4] = {0.f,0.f,0.f,0.f}, v2[4] = {0.f,0.f,0.f,0.f};
    #pragma unroll
    for (int j = 0; j < 2; ++j) {
        float x0 = acc[j][0], x1 = acc[j][1], x2 = acc[j][2], x3 = acc[j][3];
        ushort4 pk;
        pk.x = f2bf(x0); pk.y = f2bf(x1); pk.z = f2bf(x2); pk.w = f2bf(x3);
        *(ushort4*)(WhT + (size_t)(b * FOUT + (w * 2 + j) * 16 + lr) * NN + nn0) = pk;
        v1[0] += x0 * a1v[j]; v1[1] += x1 * a1v[j]; v1[2] += x2 * a1v[j]; v1[3] += x3 * a1v[j];
        v2[0] += x0 * a2v[j]; v2[1] += x1 * a2v[j]; v2[2] += x2 * a2v[j]; v2[3] += x3 * a2v[j];
    }
    #pragma unroll
    for (int m = 1; m < 16; m <<= 1) {
        #pragma unroll
        for (int r = 0; r < 4; ++r) {
            v1[r] += __shfl_xor(v1[r], m);
            v2[r] += __shfl_xor(v2[r], m);
        }
    }
    if (lr == 0) {
        #pragma unroll
        for (int r = 0; r < 4; ++r) {
            s1w[w][lk * 4 + r] = v1[r];
            s2w[w][lk * 4 + r] = v2[r];
        }
    }
    __syncthreads();
    if (t < 16) {
        s1[nglob0 + t] = s1w[0][t] + s1w[1][t] + s1w[2][t] + s1w[3][t];
        s2[nglob0 + t] = s2w[0][t] + s2w[1][t] + s2w[2][t] + s2w[3][t];
    }
}

// ---------------- Kernel 2: partial attention (j-split) -------------------
// grid = SPLIT * NB * 128 = 2048 blocks; each block: 16 rows x 512 j.
__global__ __launch_bounds__(256, 8) void k_attn_part(const int* __restrict__ adj,
                                                      const unsigned short* __restrict__ WhT,
                                                      const float* __restrict__ s1,
                                                      const float* __restrict__ s2,
                                                      float* __restrict__ num,
                                                      float* __restrict__ Zp) {
    __shared__ unsigned short Ps[2][16][72];       // P tile bf16, 2 slots
    __shared__ float hS[16][132];

    int t = threadIdx.x, w = t >> 6, l = t & 63, lr = l & 15, lk = l >> 4;
    int bi = blockIdx.x;
    int part = bi >> 9;                            // 0..3
    int rem  = bi & 511;
    int b    = rem >> 7;
    int i0   = (rem & 127) * 16;
    int j0   = part * JCH;
    int rowA = t >> 4, kA = (t & 15) * 4;

    const int*   adjp = adj + (size_t)(b * NN + i0 + rowA) * NN + j0 + kA;
    const float* s2p  = s2 + b * NN + j0 + kA;
    float s1r = s1[b * NN + i0 + rowA];

    int obase = w * 32;
    const unsigned short* Bb = WhT + (size_t)(b * FOUT + obase + lr) * NN + j0 + lk * 8;

    f32x4 acc0 = {0.f,0.f,0.f,0.f}, acc1 = {0.f,0.f,0.f,0.f};
    float zacc = 0.f;

    // software prefetch of step 0
    int4   av = *(const int4*)adjp;
    float4 sv = *(const float4*)s2p;
    bf16x8 nb00 = *(const bf16x8*)(Bb);
    bf16x8 nb01 = *(const bf16x8*)(Bb + 32);
    bf16x8 nb10 = *(const bf16x8*)(Bb + 16 * NN);
    bf16x8 nb11 = *(const bf16x8*)(Bb + 16 * NN + 32);

    for (int step = 0; step < NSTEP; ++step) {
        int slot = step & 1;
        int4 avc = av; float4 svc = sv;
        bf16x8 b00 = nb00, b01 = nb01, b10 = nb10, b11 = nb11;
        if (step < NSTEP - 1) {                    // uniform branch
            adjp += 64; s2p += 64;
            av = *(const int4*)adjp;
            sv = *(const float4*)s2p;
            const unsigned short* Bn = Bb + (step + 1) * 64;
            nb00 = *(const bf16x8*)(Bn);
            nb01 = *(const bf16x8*)(Bn + 32);
            nb10 = *(const bf16x8*)(Bn + 16 * NN);
            nb11 = *(const bf16x8*)(Bn + 16 * NN + 32);
        }

        // ---- phase A: build P tile (16 x 64) in bf16 ----
        {
            int   am[4] = {avc.x, avc.y, avc.z, avc.w};
            float ss[4] = {svc.x, svc.y, svc.z, svc.w};
            unsigned short u[4];
            #pragma unroll
            for (int i = 0; i < 4; ++i) {
                float tt  = s1r + ss[i];
                float lrl = fmaxf(tt, 0.2f * tt);  // LeakyReLU
                float pp  = (am[i] > 0) ? __expf(lrl) : 0.f;
                zacc += pp;
                u[i] = f2bf(pp);
            }
            unsigned int lo = (unsigned int)u[0] | ((unsigned int)u[1] << 16);
            unsigned int hi = (unsigned int)u[2] | ((unsigned int)u[3] << 16);
            *(uint2*)&Ps[slot][rowA][kA] = make_uint2(lo, hi);
        }
        __syncthreads();

        // ---- phase B: 4 MFMAs ----
        const unsigned short* pr = &Ps[slot][lr][lk * 8];
        bf16x8 a0 = *(const bf16x8*)pr;
        bf16x8 a1 = *(const bf16x8*)(pr + 32);
        acc0 = __builtin_amdgcn_mfma_f32_16x16x32_bf16(a0, b00, acc0, 0, 0, 0);
        acc0 = __builtin_amdgcn_mfma_f32_16x16x32_bf16(a1, b01, acc0, 0, 0, 0);
        acc1 = __builtin_amdgcn_mfma_f32_16x16x32_bf16(a0, b10, acc1, 0, 0, 0);
        acc1 = __builtin_amdgcn_mfma_f32_16x16x32_bf16(a1, b11, acc1, 0, 0, 0);
    }

    // ---- Z partial reduction (16 lanes per row) ----
    #pragma unroll
    for (int m = 1; m < 16; m <<= 1) zacc += __shfl_xor(zacc, m);
    if ((t & 15) == 0) Zp[(size_t)(part * NB + b) * NN + i0 + rowA] = zacc;

    // ---- stage raw numerator in LDS, coalesced f32 store ----
    #pragma unroll
    for (int r = 0; r < 4; ++r) {
        int row = lk * 4 + r;
        hS[row][obase + lr]      = acc0[r];
        hS[row][obase + 16 + lr] = acc1[r];
    }
    __syncthreads();

    int c0 = (t & 15) * 8;
    float* op = num + ((size_t)(part * NB + b) * NN + i0 + rowA) * FOUT + c0;
    *(float4*)op       = *(const float4*)&hS[rowA][c0];
    *(float4*)(op + 4) = *(const float4*)&hS[rowA][c0 + 4];
}

// ---------------- Kernel 3: reduce splits + LayerNorm + GELU --------------
__global__ __launch_bounds__(256) void k_final(const float* __restrict__ num,
                                               const float* __restrict__ Zp,
                                               const float* __restrict__ gamma,
                                               const float* __restrict__ beta,
                                               float* __restrict__ out) {
    int t = threadIdx.x, bi = blockIdx.x;
    int b = bi >> 7, i0 = (bi & 127) * 16;
    int rowA = t >> 4, c0 = (t & 15) * 8;
    int n = i0 + rowA;

    float Z = 0.f;
    #pragma unroll
    for (int p = 0; p < SPLIT; ++p) Z += Zp[(size_t)(p * NB + b) * NN + n];

    float x[8] = {0.f,0.f,0.f,0.f,0.f,0.f,0.f,0.f};
    #pragma unroll
    for (int p = 0; p < SPLIT; ++p) {
        const float* np = num + ((size_t)(p * NB + b) * NN + n) * FOUT + c0;
        float4 v0 = *(const float4*)np;
        float4 v1 = *(const float4*)(np + 4);
        x[0] += v0.x; x[1] += v0.y; x[2] += v0.z; x[3] += v0.w;
        x[4] += v1.x; x[5] += v1.y; x[6] += v1.z; x[7] += v1.w;
    }
    float rz = 1.f / Z;
    #pragma unroll
    for (int i = 0; i < 8; ++i) x[i] *= rz;

    float sm = 0.f, sq = 0.f;
    #pragma unroll
    for (int i = 0; i < 8; ++i) { sm += x[i]; sq += x[i] * x[i]; }
    #pragma unroll
    for (int m = 1; m < 16; m <<= 1) {
        sm += __shfl_xor(sm, m);
        sq += __shfl_xor(sq, m);
    }
    float mu  = sm * (1.f / 128.f);
    float var = sq * (1.f / 128.f) - mu * mu;
    float rs  = rsqrtf(var + 1e-5f);
    float4 g0 = *(const float4*)(gamma + c0);
    float4 g1 = *(const float4*)(gamma + c0 + 4);
    float4 e0 = *(const float4*)(beta + c0);
    float4 e1 = *(const float4*)(beta + c0 + 4);
    float gg[8] = {g0.x, g0.y, g0.z, g0.w, g1.x, g1.y, g1.z, g1.w};
    float bb[8] = {e0.x, e0.y, e0.z, e0.w, e1.x, e1.y, e1.z, e1.w};
    float y[8];
    #pragma unroll
    for (int i = 0; i < 8; ++i) {
        float v = (x[i] - mu) * rs * gg[i] + bb[i];
        y[i] = 0.5f * v * (1.f + erff(v * 0.70710678118f));
    }
    float* op = out + (size_t)(b * NN + n) * FOUT + c0;
    *(float4*)op       = make_float4(y[0], y[1], y[2], y[3]);
    *(float4*)(op + 4) = make_float4(y[4], y[5], y[6], y[7]);
}

// ---------------- launcher ----------------
extern "C" void kernel_launch(void* const* d_in, const int* in_sizes, int n_in,
                              void* d_out, int out_size, void* d_ws, size_t ws_size,
                              hipStream_t stream) {
    const float* h     = (const float*)d_in[0];
    const int*   adj   = (const int*)d_in[1];
    const float* W     = (const float*)d_in[2];
    const float* a     = (const float*)d_in[3];
    const float* gamma = (const float*)d_in[4];
    const float* beta  = (const float*)d_in[5];
    float* out = (float*)d_out;

    char* ws = (char*)d_ws;
    unsigned short* WT  = (unsigned short*)ws;                       // 64 KiB
    unsigned short* WhT = (unsigned short*)(ws + (1u << 16));        // 2 MiB
    float* s1 = (float*)(ws + 2162688);                              // 32 KiB
    float* s2 = (float*)(ws + 2195456);                              // 32 KiB
    float* Zp = (float*)(ws + 2228224);                              // 128 KiB
    float* num = (float*)(ws + 2359296);                             // 16 MiB

    hipLaunchKernelGGL(k_wt,        dim3(128),           dim3(256), 0, stream, W, WT);
    hipLaunchKernelGGL(k_wh,        dim3(512),           dim3(256), 0, stream, h, a, WT, WhT, s1, s2);
    hipLaunchKernelGGL(k_attn_part, dim3(512 * SPLIT),   dim3(256), 0, stream, adj, WhT, s1, s2, num, Zp);
    hipLaunchKernelGGL(k_final,     dim3(512),           dim3(256), 0, stream, num, Zp, gamma, beta, out);
}

// Round 3
// 58.426 us; speedup vs baseline: 1.1699x; 1.1699x over previous
//
#include <hip/hip_runtime.h>
#include <hip/hip_bf16.h>

typedef __attribute__((ext_vector_type(8))) short bf16x8;
typedef __attribute__((ext_vector_type(4))) float f32x4;

#define NB   4
#define NN   2048
#define FIN  256
#define FOUT 128
#define SPLIT 4
#define JCH  (NN / SPLIT)      // 512 j per block
#define NSTEP (JCH / 64)       // 8 steps

__device__ __forceinline__ unsigned short f2bf(float f) {
    unsigned int u = __builtin_bit_cast(unsigned int, f);
    u += 0x7fffu + ((u >> 16) & 1u);
    return (unsigned short)(u >> 16);
}

// ---------------- Kernel 0: WT[o][k] bf16 from W[k][o] f32 ----------------
__global__ __launch_bounds__(256) void k_wt(const float* __restrict__ W,
                                            unsigned short* __restrict__ WT) {
    int idx = blockIdx.x * 256 + threadIdx.x;      // 32768 = 128*256
    int k = idx & 255, o = idx >> 8;
    WT[idx] = f2bf(W[k * FOUT + o]);
}

// ---------------- Kernel 1: Wh = h@W (MFMA), writes WhT bf16 + s1,s2 ------
// 512 blocks x 16 rows; 4 waves each own a 32-wide o-quadrant.
__global__ __launch_bounds__(256) void k_wh(const float* __restrict__ h,
                                            const float* __restrict__ a,
                                            const unsigned short* __restrict__ WT,
                                            unsigned short* __restrict__ WhT,
                                            float* __restrict__ s1,
                                            float* __restrict__ s2) {
    __shared__ unsigned short hs[16][264];         // 16 rows x 256 bf16, pad 8
    __shared__ float s1w[4][16], s2w[4][16];
    int t = threadIdx.x, blk = blockIdx.x;
    int nglob0 = blk * 16;                         // block's 16-row base
    int b = nglob0 >> 11;

    // stage 16 rows of h as bf16 into LDS (1024 float4, 4 per thread)
    const float4* h4 = (const float4*)h + (size_t)blk * 1024;
    #pragma unroll
    for (int i = 0; i < 4; ++i) {
        int idx = i * 256 + t;
        float4 v = h4[idx];
        int row = idx >> 6, c4 = (idx & 63) * 4;
        unsigned int lo = (unsigned int)f2bf(v.x) | ((unsigned int)f2bf(v.y) << 16);
        unsigned int hi = (unsigned int)f2bf(v.z) | ((unsigned int)f2bf(v.w) << 16);
        *(uint2*)&hs[row][c4] = make_uint2(lo, hi);
    }
    __syncthreads();

    int w = t >> 6, l = t & 63, lr = l & 15, lk = l >> 4;
    float a1v[2], a2v[2];
    #pragma unroll
    for (int j = 0; j < 2; ++j) {
        a1v[j] = a[(w * 2 + j) * 16 + lr];
        a2v[j] = a[FOUT + (w * 2 + j) * 16 + lr];
    }
    f32x4 acc[2] = {{0.f,0.f,0.f,0.f},{0.f,0.f,0.f,0.f}};

    #pragma unroll
    for (int kk = 0; kk < 8; ++kk) {
        int k0 = kk * 32;
        bf16x8 af = *(const bf16x8*)&hs[lr][k0 + lk * 8];
        #pragma unroll
        for (int j = 0; j < 2; ++j) {
            bf16x8 bf = *(const bf16x8*)(WT + ((w * 2 + j) * 16 + lr) * 256 + k0 + lk * 8);
            acc[j] = __builtin_amdgcn_mfma_f32_16x16x32_bf16(af, bf, acc[j], 0, 0, 0);
        }
    }

    // epilogue: write WhT bf16 (transposed) and per-wave s1/s2 partials
    int nn0 = (nglob0 & 2047) + lk * 4;
    float v1[4] = {0.f,0.f,0.f,0.f}, v2[4] = {0.f,0.f,0.f,0.f};
    #pragma unroll
    for (int j = 0; j < 2; ++j) {
        float x0 = acc[j][0], x1 = acc[j][1], x2 = acc[j][2], x3 = acc[j][3];
        ushort4 pk;
        pk.x = f2bf(x0); pk.y = f2bf(x1); pk.z = f2bf(x2); pk.w = f2bf(x3);
        *(ushort4*)(WhT + (size_t)(b * FOUT + (w * 2 + j) * 16 + lr) * NN + nn0) = pk;
        v1[0] += x0 * a1v[j]; v1[1] += x1 * a1v[j]; v1[2] += x2 * a1v[j]; v1[3] += x3 * a1v[j];
        v2[0] += x0 * a2v[j]; v2[1] += x1 * a2v[j]; v2[2] += x2 * a2v[j]; v2[3] += x3 * a2v[j];
    }
    #pragma unroll
    for (int m = 1; m < 16; m <<= 1) {
        #pragma unroll
        for (int r = 0; r < 4; ++r) {
            v1[r] += __shfl_xor(v1[r], m);
            v2[r] += __shfl_xor(v2[r], m);
        }
    }
    if (lr == 0) {
        #pragma unroll
        for (int r = 0; r < 4; ++r) {
            s1w[w][lk * 4 + r] = v1[r];
            s2w[w][lk * 4 + r] = v2[r];
        }
    }
    __syncthreads();
    if (t < 16) {
        s1[nglob0 + t] = s1w[0][t] + s1w[1][t] + s1w[2][t] + s1w[3][t];
        s2[nglob0 + t] = s2w[0][t] + s2w[1][t] + s2w[2][t] + s2w[3][t];
    }
}

// ---------------- Kernel 2: partial attention (j-split) -------------------
// grid = SPLIT * NB * 128 = 2048 blocks; each block: 16 rows x 512 j.
// NOTE: plain __launch_bounds__(256). (256,8) forced VGPR 44->32 and spilled
// ~46 MB of scratch writes per dispatch (R2: WRITE_SIZE 63 MB vs 17 expected).
__global__ __launch_bounds__(256) void k_attn_part(const int* __restrict__ adj,
                                                   const unsigned short* __restrict__ WhT,
                                                   const float* __restrict__ s1,
                                                   const float* __restrict__ s2,
                                                   float* __restrict__ num,
                                                   float* __restrict__ Zp) {
    __shared__ unsigned short Ps[2][16][72];       // P tile bf16, 2 slots
    __shared__ float hS[16][132];

    int t = threadIdx.x, w = t >> 6, l = t & 63, lr = l & 15, lk = l >> 4;
    int bi = blockIdx.x;
    int part = bi >> 9;                            // 0..3
    int rem  = bi & 511;
    int b    = rem >> 7;
    int i0   = (rem & 127) * 16;
    int j0   = part * JCH;
    int rowA = t >> 4, kA = (t & 15) * 4;

    const int*   adjp = adj + (size_t)(b * NN + i0 + rowA) * NN + j0 + kA;
    const float* s2p  = s2 + b * NN + j0 + kA;
    float s1r = s1[b * NN + i0 + rowA];

    int obase = w * 32;
    const unsigned short* Bb = WhT + (size_t)(b * FOUT + obase + lr) * NN + j0 + lk * 8;

    f32x4 acc0 = {0.f,0.f,0.f,0.f}, acc1 = {0.f,0.f,0.f,0.f};
    float zacc = 0.f;

    // software prefetch of step 0
    int4   av = *(const int4*)adjp;
    float4 sv = *(const float4*)s2p;
    bf16x8 nb00 = *(const bf16x8*)(Bb);
    bf16x8 nb01 = *(const bf16x8*)(Bb + 32);
    bf16x8 nb10 = *(const bf16x8*)(Bb + 16 * NN);
    bf16x8 nb11 = *(const bf16x8*)(Bb + 16 * NN + 32);

    for (int step = 0; step < NSTEP; ++step) {
        int slot = step & 1;
        int4 avc = av; float4 svc = sv;
        bf16x8 b00 = nb00, b01 = nb01, b10 = nb10, b11 = nb11;
        if (step < NSTEP - 1) {                    // uniform branch
            adjp += 64; s2p += 64;
            av = *(const int4*)adjp;
            sv = *(const float4*)s2p;
            const unsigned short* Bn = Bb + (step + 1) * 64;
            nb00 = *(const bf16x8*)(Bn);
            nb01 = *(const bf16x8*)(Bn + 32);
            nb10 = *(const bf16x8*)(Bn + 16 * NN);
            nb11 = *(const bf16x8*)(Bn + 16 * NN + 32);
        }

        // ---- phase A: build P tile (16 x 64) in bf16 ----
        {
            int   am[4] = {avc.x, avc.y, avc.z, avc.w};
            float ss[4] = {svc.x, svc.y, svc.z, svc.w};
            unsigned short u[4];
            #pragma unroll
            for (int i = 0; i < 4; ++i) {
                float tt  = s1r + ss[i];
                float lrl = fmaxf(tt, 0.2f * tt);  // LeakyReLU
                float pp  = (am[i] > 0) ? __expf(lrl) : 0.f;
                zacc += pp;
                u[i] = f2bf(pp);
            }
            unsigned int lo = (unsigned int)u[0] | ((unsigned int)u[1] << 16);
            unsigned int hi = (unsigned int)u[2] | ((unsigned int)u[3] << 16);
            *(uint2*)&Ps[slot][rowA][kA] = make_uint2(lo, hi);
        }
        __syncthreads();

        // ---- phase B: 4 MFMAs ----
        const unsigned short* pr = &Ps[slot][lr][lk * 8];
        bf16x8 a0 = *(const bf16x8*)pr;
        bf16x8 a1 = *(const bf16x8*)(pr + 32);
        acc0 = __builtin_amdgcn_mfma_f32_16x16x32_bf16(a0, b00, acc0, 0, 0, 0);
        acc0 = __builtin_amdgcn_mfma_f32_16x16x32_bf16(a1, b01, acc0, 0, 0, 0);
        acc1 = __builtin_amdgcn_mfma_f32_16x16x32_bf16(a0, b10, acc1, 0, 0, 0);
        acc1 = __builtin_amdgcn_mfma_f32_16x16x32_bf16(a1, b11, acc1, 0, 0, 0);
    }

    // ---- Z partial reduction (16 lanes per row) ----
    #pragma unroll
    for (int m = 1; m < 16; m <<= 1) zacc += __shfl_xor(zacc, m);
    if ((t & 15) == 0) Zp[(size_t)(part * NB + b) * NN + i0 + rowA] = zacc;

    // ---- stage raw numerator in LDS, coalesced f32 store ----
    #pragma unroll
    for (int r = 0; r < 4; ++r) {
        int row = lk * 4 + r;
        hS[row][obase + lr]      = acc0[r];
        hS[row][obase + 16 + lr] = acc1[r];
    }
    __syncthreads();

    int c0 = (t & 15) * 8;
    float* op = num + ((size_t)(part * NB + b) * NN + i0 + rowA) * FOUT + c0;
    *(float4*)op       = *(const float4*)&hS[rowA][c0];
    *(float4*)(op + 4) = *(const float4*)&hS[rowA][c0 + 4];
}

// ---------------- Kernel 3: reduce splits + LayerNorm + GELU --------------
// grid = NB*NN/8 = 1024 blocks; 8 rows/block, 32 threads/row, 4 f32/thread.
__global__ __launch_bounds__(256) void k_final(const float* __restrict__ num,
                                               const float* __restrict__ Zp,
                                               const float* __restrict__ gamma,
                                               const float* __restrict__ beta,
                                               float* __restrict__ out) {
    int t = threadIdx.x, bi = blockIdx.x;
    int rowA = t >> 5;                             // 0..7
    int c0 = (t & 31) * 4;                         // 4 floats per thread
    size_t gn = (size_t)bi * 8 + rowA;             // flattened b*NN + n
    int b = (int)(gn >> 11), n = (int)(gn & 2047);

    float Z = 0.f;
    #pragma unroll
    for (int p = 0; p < SPLIT; ++p) Z += Zp[(size_t)(p * NB + b) * NN + n];

    float x[4] = {0.f, 0.f, 0.f, 0.f};
    #pragma unroll
    for (int p = 0; p < SPLIT; ++p) {
        const float* np = num + ((size_t)(p * NB + b) * NN + n) * FOUT + c0;
        float4 v0 = *(const float4*)np;
        x[0] += v0.x; x[1] += v0.y; x[2] += v0.z; x[3] += v0.w;
    }
    float rz = 1.f / Z;
    #pragma unroll
    for (int i = 0; i < 4; ++i) x[i] *= rz;

    float sm = 0.f, sq = 0.f;
    #pragma unroll
    for (int i = 0; i < 4; ++i) { sm += x[i]; sq += x[i] * x[i]; }
    #pragma unroll
    for (int m = 1; m < 32; m <<= 1) {
        sm += __shfl_xor(sm, m);
        sq += __shfl_xor(sq, m);
    }
    float mu  = sm * (1.f / 128.f);
    float var = sq * (1.f / 128.f) - mu * mu;
    float rs  = rsqrtf(var + 1e-5f);
    float4 g0 = *(const float4*)(gamma + c0);
    float4 e0 = *(const float4*)(beta + c0);
    float gg[4] = {g0.x, g0.y, g0.z, g0.w};
    float bb[4] = {e0.x, e0.y, e0.z, e0.w};
    float y[4];
    #pragma unroll
    for (int i = 0; i < 4; ++i) {
        float v = (x[i] - mu) * rs * gg[i] + bb[i];
        y[i] = 0.5f * v * (1.f + erff(v * 0.70710678118f));
    }
    float* op = out + gn * FOUT + c0;
    *(float4*)op = make_float4(y[0], y[1], y[2], y[3]);
}

// ---------------- launcher ----------------
extern "C" void kernel_launch(void* const* d_in, const int* in_sizes, int n_in,
                              void* d_out, int out_size, void* d_ws, size_t ws_size,
                              hipStream_t stream) {
    const float* h     = (const float*)d_in[0];
    const int*   adj   = (const int*)d_in[1];
    const float* W     = (const float*)d_in[2];
    const float* a     = (const float*)d_in[3];
    const float* gamma = (const float*)d_in[4];
    const float* beta  = (const float*)d_in[5];
    float* out = (float*)d_out;

    char* ws = (char*)d_ws;
    unsigned short* WT  = (unsigned short*)ws;                       // 64 KiB
    unsigned short* WhT = (unsigned short*)(ws + (1u << 16));        // 2 MiB
    float* s1 = (float*)(ws + 2162688);                              // 32 KiB
    float* s2 = (float*)(ws + 2195456);                              // 32 KiB
    float* Zp = (float*)(ws + 2228224);                              // 128 KiB
    float* num = (float*)(ws + 2359296);                             // 16 MiB

    hipLaunchKernelGGL(k_wt,        dim3(128),         dim3(256), 0, stream, W, WT);
    hipLaunchKernelGGL(k_wh,        dim3(512),         dim3(256), 0, stream, h, a, WT, WhT, s1, s2);
    hipLaunchKernelGGL(k_attn_part, dim3(512 * SPLIT), dim3(256), 0, stream, adj, WhT, s1, s2, num, Zp);
    hipLaunchKernelGGL(k_final,     dim3(1024),        dim3(256), 0, stream, num, Zp, gamma, beta, out);
}